// Round 14
// baseline (570.986 us; speedup 1.0000x reference)
//
#include <hip/hip_runtime.h>
#include <stdint.h>

#define N_TOK 196
#define DIM   128
#define HEADS 4
#define NWIN  64
#define SCALE 0.17677669529663687f
#define LOG2E 1.4426950408889634f
#define PS_LD 232   // P-strip LDS stride (ushorts)

typedef __bf16 bf16x8 __attribute__((ext_vector_type(8)));
typedef float  f32x4  __attribute__((ext_vector_type(4)));

__device__ __forceinline__ unsigned short f2bf(float f) {
  unsigned r;
  asm("v_cvt_pk_bf16_f32 %0, %1, %2" : "=v"(r) : "v"(f), "v"(f));
  return (unsigned short)r;
}
__device__ __forceinline__ unsigned pack2(float a, float b) {
  unsigned r;
  asm("v_cvt_pk_bf16_f32 %0, %1, %2" : "=v"(r) : "v"(a), "v"(b));
  return r;
}
__device__ __forceinline__ float fexp2(float x) {
  float r;
  asm("v_exp_f32 %0, %1" : "=v"(r) : "v"(x));
  return r;
}

// ---------------------------------------------------------------------------
// Kernel A: prep — pos-bias MLP table (729x4), bf16-transposed weights.
// ---------------------------------------------------------------------------
__global__ void prep_kernel(
    const float* __restrict__ qkv_w, const float* __restrict__ proj_w,
    const float* __restrict__ biases,
    const float* __restrict__ pos_proj_w, const float* __restrict__ pos_proj_b,
    const float* __restrict__ ln1_w, const float* __restrict__ ln1_b,
    const float* __restrict__ fc1_w, const float* __restrict__ fc1_b,
    const float* __restrict__ ln2_w, const float* __restrict__ ln2_b,
    const float* __restrict__ fc2_w, const float* __restrict__ fc2_b,
    const float* __restrict__ ln3_w, const float* __restrict__ ln3_b,
    const float* __restrict__ fc3_w, const float* __restrict__ fc3_b,
    unsigned short* __restrict__ wqkv_t, unsigned short* __restrict__ wproj_t,
    float* __restrict__ ptab)
{
  const int tid = threadIdx.x, blk = blockIdx.x;
  if (blk < 3) {
    int r = blk * 256 + tid;
    if (r < 729) {
      float v[8], t[8];
      float b0 = biases[2*r], b1 = biases[2*r+1];
      for (int j = 0; j < 8; ++j)
        v[j] = b0 * pos_proj_w[j] + b1 * pos_proj_w[8+j] + pos_proj_b[j];
      const float* lws[3] = {ln1_w, ln2_w, ln3_w};
      const float* lbs[3] = {ln1_b, ln2_b, ln3_b};
      const float* fws[3] = {fc1_w, fc2_w, fc3_w};
      const float* fbs[3] = {fc1_b, fc2_b, fc3_b};
      for (int L = 0; L < 3; ++L) {
        float mu = 0.f;  for (int j=0;j<8;++j) mu += v[j];  mu *= 0.125f;
        float var = 0.f; for (int j=0;j<8;++j){ float d=v[j]-mu; var+=d*d; } var *= 0.125f;
        float rs = rsqrtf(var + 1e-5f);
        for (int j=0;j<8;++j){ float u=(v[j]-mu)*rs*lws[L][j]+lbs[L][j]; t[j]=fmaxf(u,0.f); }
        int nout = (L==2) ? 4 : 8;
        for (int o=0;o<nout;++o){ float s=fbs[L][o]; for (int j=0;j<8;++j) s += t[j]*fws[L][j*nout+o]; v[o]=s; }
      }
      for (int hh=0; hh<4; ++hh) ptab[r*4+hh] = v[hh];
    }
  } else if (blk < 7) {
    for (int i = (blk-3)*256 + tid; i < 384*128; i += 1024) {
      int col = i >> 7, k = i & 127;
      wqkv_t[i] = f2bf(qkv_w[k*384 + col]);
    }
  } else {
    for (int i = tid; i < 128*128; i += 256) {
      int col = i >> 7, k = i & 127;
      wproj_t[i] = f2bf(proj_w[k*128 + col]);
    }
  }
}

// ---------------------------------------------------------------------------
// Kernel A2: combT[w][h][k][q] = (bias + mask) * LOG2E  (196x196, f32)
// ---------------------------------------------------------------------------
__global__ void comb_kernel(const int* __restrict__ rel_idx,
                            const float* __restrict__ ptab,
                            const float* __restrict__ mask,
                            float* __restrict__ combT)
{
  int blk = blockIdx.x;            // w*196 + k
  int w = blk / 196, k = blk - w*196;
  int q = threadIdx.x;
  if (q < N_TOK) {
    int idx = rel_idx[q*N_TOK + k];
    float mv = mask[((size_t)w*N_TOK + q)*N_TOK + k];
    #pragma unroll
    for (int h = 0; h < 4; ++h)
      combT[((size_t)(w*4 + h)*196 + k)*196 + q] = (ptab[idx*4 + h] + mv) * LOG2E;
  }
}

// ---------------------------------------------------------------------------
// Kernel B1: qkv GEMM per b — weight-stationary, no LDS.
// q is pre-scaled by SCALE*LOG2E (softmax in base 2).
// ---------------------------------------------------------------------------
__launch_bounds__(256, 2)
__global__ void qkv_kernel(const float* __restrict__ x,
                           const float* __restrict__ qkv_b,
                           const unsigned short* __restrict__ wqkv_t,
                           unsigned short* __restrict__ q_g,
                           unsigned short* __restrict__ k_g,
                           unsigned short* __restrict__ vt_g)
{
  const int tid = threadIdx.x;
  const int wave = tid >> 6, lane = tid & 63, lr = lane & 15, lg = lane >> 4;
  const int b = blockIdx.x;
  const float* xb = x + (size_t)b * (N_TOK*DIM);

  bf16x8 wf[6][4];
  float  bq[6];
  f32x4  bv[6];
  #pragma unroll
  for (int i = 0; i < 6; ++i) {
    const int g = wave*6 + i;
    #pragma unroll
    for (int kc = 0; kc < 4; ++kc)
      wf[i][kc] = *(const bf16x8*)(wqkv_t + (g*16 + lr)*128 + kc*32 + lg*8);
    if (g < 16) {
      bq[i] = qkv_b[g*16 + lr];
      bv[i] = (f32x4){0.f,0.f,0.f,0.f};
    } else {
      bq[i] = 0.f;
      #pragma unroll
      for (int r = 0; r < 4; ++r) bv[i][r] = qkv_b[g*16 + lg*4 + r];
    }
  }

  auto load_xf = [&](int rt, bf16x8* xf) {
    const int arow = rt*16 + lr;
    #pragma unroll
    for (int kc = 0; kc < 4; ++kc) {
      union { unsigned u[4]; bf16x8 v; } c;
      if (arow < N_TOK) {
        float4 p0 = *(const float4*)(xb + arow*DIM + kc*32 + lg*8);
        float4 p1 = *(const float4*)(xb + arow*DIM + kc*32 + lg*8 + 4);
        c.u[0] = pack2(p0.x, p0.y); c.u[1] = pack2(p0.z, p0.w);
        c.u[2] = pack2(p1.x, p1.y); c.u[3] = pack2(p1.z, p1.w);
      } else {
        c.u[0] = c.u[1] = c.u[2] = c.u[3] = 0u;
      }
      xf[kc] = c.v;
    }
  };

  bf16x8 xf[4], xfn[4];
  load_xf(0, xf);
  for (int rt = 0; rt < 13; ++rt) {
    if (rt < 12) load_xf(rt + 1, xfn);
    #pragma unroll
    for (int i = 0; i < 6; ++i) {
      const int g = wave*6 + i;
      f32x4 acc = {0.f,0.f,0.f,0.f};
      if (g >= 16) {                          // V: swapped operands -> V^T
        #pragma unroll
        for (int kc = 0; kc < 4; ++kc)
          acc = __builtin_amdgcn_mfma_f32_16x16x32_bf16(wf[i][kc], xf[kc], acc, 0, 0, 0);
        const int dt = g - 16;
        #pragma unroll
        for (int r = 0; r < 4; ++r)
          vt_g[((size_t)b*128 + dt*16 + lg*4 + r)*224 + rt*16 + lr] =
              f2bf(acc[r] + bv[i][r]);
      } else {
        #pragma unroll
        for (int kc = 0; kc < 4; ++kc)
          acc = __builtin_amdgcn_mfma_f32_16x16x32_bf16(xf[kc], wf[i][kc], acc, 0, 0, 0);
        const int cs = (g < 8) ? g*16 : (g-8)*16;
        unsigned short* dst = (g < 8) ? q_g : k_g;
        const float mul = (g < 8) ? (SCALE * LOG2E) : 1.f;
        #pragma unroll
        for (int r = 0; r < 4; ++r)
          dst[((size_t)(b*4 + (cs>>5))*208 + rt*16 + lg*4 + r)*32 + (cs&31) + lr] =
              f2bf((acc[r] + bq[i]) * mul);
      }
    }
    #pragma unroll
    for (int kc = 0; kc < 4; ++kc) xf[kc] = xfn[kc];
  }
}

// ---------------------------------------------------------------------------
// Kernel B2: attention — proven round-11 body/grid. Output written as BF16
// into this head's own q_g slot (q fully consumed first; same rows, same
// wave, program-ordered -> race-free). launch_bounds 3->5 blocks/CU.
// ---------------------------------------------------------------------------
__launch_bounds__(256, 5)
__global__ void attn_kernel(unsigned short* q_g,
                            const unsigned short* __restrict__ k_g,
                            const unsigned short* __restrict__ vt_g,
                            const float* __restrict__ combT)
{
  __shared__ unsigned short psw_all[4*16*PS_LD];   // 29,696 B
  const int tid = threadIdx.x;
  const int wave = tid >> 6, lane = tid & 63, lr = lane & 15, lg = lane >> 4;
  // bijective swizzle: 16 consecutive co-XCD blocks share one combT table
  const int wgt = blockIdx.x;
  const int v  = (wgt & 7)*512 + (wgt >> 3);
  const int bi = v & 15, wh = v >> 4;
  const int b  = bi*64 + (wh >> 2), h = wh & 3;
  const int bh = b*4 + h;
  unsigned short* psw = psw_all + wave*(16*PS_LD);

  // zero pad P columns 208-223 (read by last PV MFMA)
  for (int i = lane; i < 256; i += 64)
    psw[(i >> 4)*PS_LD + 208 + (i & 15)] = 0;

  unsigned short* qb = q_g + (size_t)bh*(208*32);   // read q, then write out
  const unsigned short* kb = k_g + (size_t)bh*(208*32);
  const unsigned short* vb = vt_g + (size_t)bh*(32*224);
  const float* cbase = combT + (size_t)wh*(196*196);

  // hoist K fragments (qt-invariant): 13 x 4 VGPR
  bf16x8 kfr[13];
  #pragma unroll
  for (int kt = 0; kt < 13; ++kt)
    kfr[kt] = *(const bf16x8*)(kb + (kt*16 + lr)*32 + lg*8);

  for (int qt = wave; qt < 13; qt += 4) {
    bf16x8 aq = *(const bf16x8*)(qb + (qt*16 + lr)*32 + lg*8);

    // load bias+mask directly into the accumulator (consumed as MFMA C)
    f32x4 s[13];
    #pragma unroll
    for (int kt = 0; kt < 13; ++kt) {
      int c = kt*16 + lr;
      s[kt] = (c < N_TOK) ? *(const f32x4*)(cbase + (size_t)c*196 + qt*16 + lg*4)
                          : (f32x4){0.f,0.f,0.f,0.f};
    }

    __builtin_amdgcn_s_setprio(1);
    #pragma unroll
    for (int kt = 0; kt < 13; ++kt)
      s[kt] = __builtin_amdgcn_mfma_f32_16x16x32_bf16(aq, kfr[kt], s[kt], 0, 0, 0);
    __builtin_amdgcn_s_setprio(0);

    // 2^s (q and combT pre-scaled by log2e); zero pad cols
    #pragma unroll
    for (int kt = 0; kt < 13; ++kt) {
      #pragma unroll
      for (int r = 0; r < 4; ++r) s[kt][r] = fexp2(s[kt][r]);
    }
    if (lr >= 4) s[12] = (f32x4){0.f,0.f,0.f,0.f};

    // row sums (16-lane spread), deferred normalization
    float linv[4];
    #pragma unroll
    for (int r = 0; r < 4; ++r) {
      float ssum = 0.f;
      #pragma unroll
      for (int kt = 0; kt < 13; ++kt) ssum += s[kt][r];
      #pragma unroll
      for (int off = 1; off < 16; off <<= 1) ssum += __shfl_xor(ssum, off);
      linv[r] = 1.f / ssum;
    }

    // P strip -> LDS (bf16, unnormalized, cols 0-207)
    #pragma unroll
    for (int r = 0; r < 4; ++r) {
      int prow = lg*4 + r;
      #pragma unroll
      for (int kt = 0; kt < 13; ++kt)
        psw[prow*PS_LD + kt*16 + lr] = f2bf(s[kt][r]);
    }
    asm volatile("s_waitcnt lgkmcnt(0)" ::: "memory");

    // PV over 224 tokens (P cols 208-223 are zero); output bf16 into q_g slot
    __builtin_amdgcn_s_setprio(1);
    #pragma unroll
    for (int c2 = 0; c2 < 2; ++c2) {
      f32x4 o = {0.f,0.f,0.f,0.f};
      #pragma unroll
      for (int kc = 0; kc < 7; ++kc) {
        bf16x8 ap = *(const bf16x8*)(psw + lr*PS_LD + kc*32 + lg*8);
        bf16x8 bv = *(const bf16x8*)(vb + (c2*16 + lr)*224 + kc*32 + lg*8);
        o = __builtin_amdgcn_mfma_f32_16x16x32_bf16(ap, bv, o, 0, 0, 0);
      }
      #pragma unroll
      for (int r = 0; r < 4; ++r) {
        int row = qt*16 + lg*4 + r;
        if (row < N_TOK)
          qb[row*32 + c2*16 + lr] = f2bf(o[r] * linv[r]);
      }
    }
    __builtin_amdgcn_s_setprio(0);
  }
}

// ---------------------------------------------------------------------------
// Kernel C: projection reading bf16 attnout DIRECTLY from q_g (no LDS,
// no sync). att[(b*4+kc)*208 + tok][32] holds head kc's 32 cols of row tok.
// ---------------------------------------------------------------------------
__launch_bounds__(256, 4)
__global__ void proj_kernel(const unsigned short* __restrict__ att,
                            const unsigned short* __restrict__ wproj_t,
                            const float* __restrict__ proj_b,
                            float* __restrict__ out)
{
  const int tid = threadIdx.x;
  const int wave = tid >> 6, lane = tid & 63, lr = lane & 15, lg = lane >> 4;
  const int row0 = blockIdx.x * 64;

  bf16x8 wf[2][4];
  float bias[2];
  #pragma unroll
  for (int i = 0; i < 2; ++i) {
    int ct = wave*2 + i;
    bias[i] = proj_b[ct*16 + lr];
    #pragma unroll
    for (int kc = 0; kc < 4; ++kc)
      wf[i][kc] = *(const bf16x8*)(wproj_t + (ct*16 + lr)*128 + kc*32 + lg*8);
  }

  for (int rt = 0; rt < 4; ++rt) {
    const int g = row0 + rt*16 + lr;       // global row (b*196 + tok)
    const int b = g / 196, tok = g - b*196;
    bf16x8 af[4];
    #pragma unroll
    for (int kc = 0; kc < 4; ++kc)         // k-chunk kc == head kc
      af[kc] = *(const bf16x8*)(att + ((size_t)(b*4 + kc)*208 + tok)*32 + lg*8);
    #pragma unroll
    for (int i = 0; i < 2; ++i) {
      f32x4 acc = {0.f,0.f,0.f,0.f};
      #pragma unroll
      for (int kc = 0; kc < 4; ++kc)
        acc = __builtin_amdgcn_mfma_f32_16x16x32_bf16(af[kc], wf[i][kc], acc, 0, 0, 0);
      #pragma unroll
      for (int r = 0; r < 4; ++r)
        out[(size_t)(row0 + rt*16 + lg*4 + r)*DIM + (wave*2 + i)*16 + lr] =
            acc[r] + bias[i];
    }
  }
}

// ---------------------------------------------------------------------------
extern "C" void kernel_launch(void* const* d_in, const int* in_sizes, int n_in,
                              void* d_out, int out_size, void* d_ws, size_t ws_size,
                              hipStream_t stream)
{
  const float* x          = (const float*)d_in[0];
  const float* mask       = (const float*)d_in[1];
  const float* qkv_w      = (const float*)d_in[2];
  const float* qkv_b      = (const float*)d_in[3];
  const float* proj_w     = (const float*)d_in[4];
  const float* proj_b     = (const float*)d_in[5];
  const float* pos_proj_w = (const float*)d_in[6];
  const float* pos_proj_b = (const float*)d_in[7];
  const float* ln1_w = (const float*)d_in[8];
  const float* ln1_b = (const float*)d_in[9];
  const float* fc1_w = (const float*)d_in[10];
  const float* fc1_b = (const float*)d_in[11];
  const float* ln2_w = (const float*)d_in[12];
  const float* ln2_b = (const float*)d_in[13];
  const float* fc2_w = (const float*)d_in[14];
  const float* fc2_b = (const float*)d_in[15];
  const float* ln3_w = (const float*)d_in[16];
  const float* ln3_b = (const float*)d_in[17];
  const float* fc3_w = (const float*)d_in[18];
  const float* fc3_b = (const float*)d_in[19];
  const float* biases = (const float*)d_in[20];
  const int*   rel_idx = (const int*)d_in[21];

  // ws layout (~207 MB — the proven-working layout)
  char* ws = (char*)d_ws;
  unsigned short* wqkv_t  = (unsigned short*)(ws);
  unsigned short* wproj_t = (unsigned short*)(ws + 98304);
  float*          ptab    = (float*)(ws + 131072);
  float*          combT   = (float*)(ws + 147456);              // 39,337,984 B
  unsigned short* q_g     = (unsigned short*)(ws + 39485696);   // 54,525,952 B
  unsigned short* k_g     = (unsigned short*)(ws + 94011648);   // 54,525,952 B
  unsigned short* vt_g    = (unsigned short*)(ws + 148537600);  // 58,720,256 B
  float* out = (float*)d_out;

  prep_kernel<<<8, 256, 0, stream>>>(qkv_w, proj_w, biases, pos_proj_w, pos_proj_b,
      ln1_w, ln1_b, fc1_w, fc1_b, ln2_w, ln2_b, fc2_w, fc2_b,
      ln3_w, ln3_b, fc3_w, fc3_b, wqkv_t, wproj_t, ptab);
  comb_kernel<<<NWIN*N_TOK, 256, 0, stream>>>(rel_idx, ptab, mask, combT);
  qkv_kernel<<<1024, 256, 0, stream>>>(x, qkv_b, wqkv_t, q_g, k_g, vt_g);
  attn_kernel<<<1024*HEADS, 256, 0, stream>>>(q_g, k_g, vt_g, combT);
  proj_kernel<<<(1024*N_TOK)/64, 256, 0, stream>>>(q_g, wproj_t, proj_b, out);
}

// Round 15
// 341.185 us; speedup vs baseline: 1.6735x; 1.6735x over previous
//
#include <hip/hip_runtime.h>
#include <stdint.h>

#define N_TOK 196
#define DIM   128
#define HEADS 4
#define NWIN  64
#define SCALE 0.17677669529663687f
#define LOG2E 1.4426950408889634f
#define PS_LD 232   // P-strip LDS stride (ushorts)

typedef __bf16 bf16x8 __attribute__((ext_vector_type(8)));
typedef float  f32x4  __attribute__((ext_vector_type(4)));

__device__ __forceinline__ unsigned short f2bf(float f) {
  unsigned r;
  asm("v_cvt_pk_bf16_f32 %0, %1, %2" : "=v"(r) : "v"(f), "v"(f));
  return (unsigned short)r;
}
__device__ __forceinline__ unsigned pack2(float a, float b) {
  unsigned r;
  asm("v_cvt_pk_bf16_f32 %0, %1, %2" : "=v"(r) : "v"(a), "v"(b));
  return r;
}
__device__ __forceinline__ float fexp2(float x) {
  float r;
  asm("v_exp_f32 %0, %1" : "=v"(r) : "v"(x));
  return r;
}

// ---------------------------------------------------------------------------
// Kernel A: prep — pos-bias MLP table (729x4), bf16-transposed weights.
// ---------------------------------------------------------------------------
__global__ void prep_kernel(
    const float* __restrict__ qkv_w, const float* __restrict__ proj_w,
    const float* __restrict__ biases,
    const float* __restrict__ pos_proj_w, const float* __restrict__ pos_proj_b,
    const float* __restrict__ ln1_w, const float* __restrict__ ln1_b,
    const float* __restrict__ fc1_w, const float* __restrict__ fc1_b,
    const float* __restrict__ ln2_w, const float* __restrict__ ln2_b,
    const float* __restrict__ fc2_w, const float* __restrict__ fc2_b,
    const float* __restrict__ ln3_w, const float* __restrict__ ln3_b,
    const float* __restrict__ fc3_w, const float* __restrict__ fc3_b,
    unsigned short* __restrict__ wqkv_t, unsigned short* __restrict__ wproj_t,
    float* __restrict__ ptab)
{
  const int tid = threadIdx.x, blk = blockIdx.x;
  if (blk < 3) {
    int r = blk * 256 + tid;
    if (r < 729) {
      float v[8], t[8];
      float b0 = biases[2*r], b1 = biases[2*r+1];
      for (int j = 0; j < 8; ++j)
        v[j] = b0 * pos_proj_w[j] + b1 * pos_proj_w[8+j] + pos_proj_b[j];
      const float* lws[3] = {ln1_w, ln2_w, ln3_w};
      const float* lbs[3] = {ln1_b, ln2_b, ln3_b};
      const float* fws[3] = {fc1_w, fc2_w, fc3_w};
      const float* fbs[3] = {fc1_b, fc2_b, fc3_b};
      for (int L = 0; L < 3; ++L) {
        float mu = 0.f;  for (int j=0;j<8;++j) mu += v[j];  mu *= 0.125f;
        float var = 0.f; for (int j=0;j<8;++j){ float d=v[j]-mu; var+=d*d; } var *= 0.125f;
        float rs = rsqrtf(var + 1e-5f);
        for (int j=0;j<8;++j){ float u=(v[j]-mu)*rs*lws[L][j]+lbs[L][j]; t[j]=fmaxf(u,0.f); }
        int nout = (L==2) ? 4 : 8;
        for (int o=0;o<nout;++o){ float s=fbs[L][o]; for (int j=0;j<8;++j) s += t[j]*fws[L][j*nout+o]; v[o]=s; }
      }
      for (int hh=0; hh<4; ++hh) ptab[r*4+hh] = v[hh];
    }
  } else if (blk < 7) {
    for (int i = (blk-3)*256 + tid; i < 384*128; i += 1024) {
      int col = i >> 7, k = i & 127;
      wqkv_t[i] = f2bf(qkv_w[k*384 + col]);
    }
  } else {
    for (int i = tid; i < 128*128; i += 256) {
      int col = i >> 7, k = i & 127;
      wproj_t[i] = f2bf(proj_w[k*128 + col]);
    }
  }
}

// ---------------------------------------------------------------------------
// Kernel A2: combT[w][h][k][q] = (bias + mask) * LOG2E  (196x196, f32)
// ---------------------------------------------------------------------------
__global__ void comb_kernel(const int* __restrict__ rel_idx,
                            const float* __restrict__ ptab,
                            const float* __restrict__ mask,
                            float* __restrict__ combT)
{
  int blk = blockIdx.x;            // w*196 + k
  int w = blk / 196, k = blk - w*196;
  int q = threadIdx.x;
  if (q < N_TOK) {
    int idx = rel_idx[q*N_TOK + k];
    float mv = mask[((size_t)w*N_TOK + q)*N_TOK + k];
    #pragma unroll
    for (int h = 0; h < 4; ++h)
      combT[((size_t)(w*4 + h)*196 + k)*196 + q] = (ptab[idx*4 + h] + mv) * LOG2E;
  }
}

// ---------------------------------------------------------------------------
// Kernel B1: qkv GEMM per b — weight-stationary, no LDS.
// q is pre-scaled by SCALE*LOG2E (softmax in base 2).
// ---------------------------------------------------------------------------
__launch_bounds__(256, 2)
__global__ void qkv_kernel(const float* __restrict__ x,
                           const float* __restrict__ qkv_b,
                           const unsigned short* __restrict__ wqkv_t,
                           unsigned short* __restrict__ q_g,
                           unsigned short* __restrict__ k_g,
                           unsigned short* __restrict__ vt_g)
{
  const int tid = threadIdx.x;
  const int wave = tid >> 6, lane = tid & 63, lr = lane & 15, lg = lane >> 4;
  const int b = blockIdx.x;
  const float* xb = x + (size_t)b * (N_TOK*DIM);

  bf16x8 wf[6][4];
  float  bq[6];
  f32x4  bv[6];
  #pragma unroll
  for (int i = 0; i < 6; ++i) {
    const int g = wave*6 + i;
    #pragma unroll
    for (int kc = 0; kc < 4; ++kc)
      wf[i][kc] = *(const bf16x8*)(wqkv_t + (g*16 + lr)*128 + kc*32 + lg*8);
    if (g < 16) {
      bq[i] = qkv_b[g*16 + lr];
      bv[i] = (f32x4){0.f,0.f,0.f,0.f};
    } else {
      bq[i] = 0.f;
      #pragma unroll
      for (int r = 0; r < 4; ++r) bv[i][r] = qkv_b[g*16 + lg*4 + r];
    }
  }

  auto load_xf = [&](int rt, bf16x8* xf) {
    const int arow = rt*16 + lr;
    #pragma unroll
    for (int kc = 0; kc < 4; ++kc) {
      union { unsigned u[4]; bf16x8 v; } c;
      if (arow < N_TOK) {
        float4 p0 = *(const float4*)(xb + arow*DIM + kc*32 + lg*8);
        float4 p1 = *(const float4*)(xb + arow*DIM + kc*32 + lg*8 + 4);
        c.u[0] = pack2(p0.x, p0.y); c.u[1] = pack2(p0.z, p0.w);
        c.u[2] = pack2(p1.x, p1.y); c.u[3] = pack2(p1.z, p1.w);
      } else {
        c.u[0] = c.u[1] = c.u[2] = c.u[3] = 0u;
      }
      xf[kc] = c.v;
    }
  };

  bf16x8 xf[4], xfn[4];
  load_xf(0, xf);
  for (int rt = 0; rt < 13; ++rt) {
    if (rt < 12) load_xf(rt + 1, xfn);
    #pragma unroll
    for (int i = 0; i < 6; ++i) {
      const int g = wave*6 + i;
      f32x4 acc = {0.f,0.f,0.f,0.f};
      if (g >= 16) {                          // V: swapped operands -> V^T
        #pragma unroll
        for (int kc = 0; kc < 4; ++kc)
          acc = __builtin_amdgcn_mfma_f32_16x16x32_bf16(wf[i][kc], xf[kc], acc, 0, 0, 0);
        const int dt = g - 16;
        #pragma unroll
        for (int r = 0; r < 4; ++r)
          vt_g[((size_t)b*128 + dt*16 + lg*4 + r)*224 + rt*16 + lr] =
              f2bf(acc[r] + bv[i][r]);
      } else {
        #pragma unroll
        for (int kc = 0; kc < 4; ++kc)
          acc = __builtin_amdgcn_mfma_f32_16x16x32_bf16(xf[kc], wf[i][kc], acc, 0, 0, 0);
        const int cs = (g < 8) ? g*16 : (g-8)*16;
        unsigned short* dst = (g < 8) ? q_g : k_g;
        const float mul = (g < 8) ? (SCALE * LOG2E) : 1.f;
        #pragma unroll
        for (int r = 0; r < 4; ++r)
          dst[((size_t)(b*4 + (cs>>5))*208 + rt*16 + lg*4 + r)*32 + (cs&31) + lr] =
              f2bf((acc[r] + bq[i]) * mul);
      }
    }
    #pragma unroll
    for (int kc = 0; kc < 4; ++kc) xf[kc] = xfn[kc];
  }
}

// ---------------------------------------------------------------------------
// Kernel B2: attention — proven round-12 body/grid/launch_bounds(256,3).
// Output written as BF16 into this head's own q_g slot (q fully consumed
// first; same rows, same wave, program-ordered -> race-free).
// ---------------------------------------------------------------------------
__launch_bounds__(256, 3)
__global__ void attn_kernel(unsigned short* q_g,
                            const unsigned short* __restrict__ k_g,
                            const unsigned short* __restrict__ vt_g,
                            const float* __restrict__ combT)
{
  __shared__ unsigned short psw_all[4*16*PS_LD];   // 29,696 B
  const int tid = threadIdx.x;
  const int wave = tid >> 6, lane = tid & 63, lr = lane & 15, lg = lane >> 4;
  // bijective swizzle: 16 consecutive co-XCD blocks share one combT table
  const int wgt = blockIdx.x;
  const int v  = (wgt & 7)*512 + (wgt >> 3);
  const int bi = v & 15, wh = v >> 4;
  const int b  = bi*64 + (wh >> 2), h = wh & 3;
  const int bh = b*4 + h;
  unsigned short* psw = psw_all + wave*(16*PS_LD);

  // zero pad P columns 208-223 (read by last PV MFMA)
  for (int i = lane; i < 256; i += 64)
    psw[(i >> 4)*PS_LD + 208 + (i & 15)] = 0;

  unsigned short* qb = q_g + (size_t)bh*(208*32);   // read q, then write out
  const unsigned short* kb = k_g + (size_t)bh*(208*32);
  const unsigned short* vb = vt_g + (size_t)bh*(32*224);
  const float* cbase = combT + (size_t)wh*(196*196);

  // hoist K fragments (qt-invariant): 13 x 4 VGPR
  bf16x8 kfr[13];
  #pragma unroll
  for (int kt = 0; kt < 13; ++kt)
    kfr[kt] = *(const bf16x8*)(kb + (kt*16 + lr)*32 + lg*8);

  for (int qt = wave; qt < 13; qt += 4) {
    bf16x8 aq = *(const bf16x8*)(qb + (qt*16 + lr)*32 + lg*8);

    // load bias+mask directly into the accumulator (consumed as MFMA C)
    f32x4 s[13];
    #pragma unroll
    for (int kt = 0; kt < 13; ++kt) {
      int c = kt*16 + lr;
      s[kt] = (c < N_TOK) ? *(const f32x4*)(cbase + (size_t)c*196 + qt*16 + lg*4)
                          : (f32x4){0.f,0.f,0.f,0.f};
    }

    __builtin_amdgcn_s_setprio(1);
    #pragma unroll
    for (int kt = 0; kt < 13; ++kt)
      s[kt] = __builtin_amdgcn_mfma_f32_16x16x32_bf16(aq, kfr[kt], s[kt], 0, 0, 0);
    __builtin_amdgcn_s_setprio(0);

    // 2^s (q and combT pre-scaled by log2e); zero pad cols
    #pragma unroll
    for (int kt = 0; kt < 13; ++kt) {
      #pragma unroll
      for (int r = 0; r < 4; ++r) s[kt][r] = fexp2(s[kt][r]);
    }
    if (lr >= 4) s[12] = (f32x4){0.f,0.f,0.f,0.f};

    // row sums (16-lane spread), deferred normalization
    float linv[4];
    #pragma unroll
    for (int r = 0; r < 4; ++r) {
      float ssum = 0.f;
      #pragma unroll
      for (int kt = 0; kt < 13; ++kt) ssum += s[kt][r];
      #pragma unroll
      for (int off = 1; off < 16; off <<= 1) ssum += __shfl_xor(ssum, off);
      linv[r] = 1.f / ssum;
    }

    // P strip -> LDS (bf16, unnormalized, cols 0-207)
    #pragma unroll
    for (int r = 0; r < 4; ++r) {
      int prow = lg*4 + r;
      #pragma unroll
      for (int kt = 0; kt < 13; ++kt)
        psw[prow*PS_LD + kt*16 + lr] = f2bf(s[kt][r]);
    }
    asm volatile("s_waitcnt lgkmcnt(0)" ::: "memory");

    // PV over 224 tokens (P cols 208-223 are zero); output bf16 into q_g slot
    __builtin_amdgcn_s_setprio(1);
    #pragma unroll
    for (int c2 = 0; c2 < 2; ++c2) {
      f32x4 o = {0.f,0.f,0.f,0.f};
      #pragma unroll
      for (int kc = 0; kc < 7; ++kc) {
        bf16x8 ap = *(const bf16x8*)(psw + lr*PS_LD + kc*32 + lg*8);
        bf16x8 bv = *(const bf16x8*)(vb + (c2*16 + lr)*224 + kc*32 + lg*8);
        o = __builtin_amdgcn_mfma_f32_16x16x32_bf16(ap, bv, o, 0, 0, 0);
      }
      #pragma unroll
      for (int r = 0; r < 4; ++r) {
        int row = qt*16 + lg*4 + r;
        if (row < N_TOK)
          qb[row*32 + c2*16 + lr] = f2bf(o[r] * linv[r]);
      }
    }
    __builtin_amdgcn_s_setprio(0);
  }
}

// ---------------------------------------------------------------------------
// Kernel C: projection reading bf16 attnout DIRECTLY from q_g (no LDS,
// no sync). att[(b*4+kc)*208 + tok][32] holds head kc's 32 cols of row tok.
// ---------------------------------------------------------------------------
__launch_bounds__(256, 4)
__global__ void proj_kernel(const unsigned short* __restrict__ att,
                            const unsigned short* __restrict__ wproj_t,
                            const float* __restrict__ proj_b,
                            float* __restrict__ out)
{
  const int tid = threadIdx.x;
  const int wave = tid >> 6, lane = tid & 63, lr = lane & 15, lg = lane >> 4;
  const int row0 = blockIdx.x * 64;

  bf16x8 wf[2][4];
  float bias[2];
  #pragma unroll
  for (int i = 0; i < 2; ++i) {
    int ct = wave*2 + i;
    bias[i] = proj_b[ct*16 + lr];
    #pragma unroll
    for (int kc = 0; kc < 4; ++kc)
      wf[i][kc] = *(const bf16x8*)(wproj_t + (ct*16 + lr)*128 + kc*32 + lg*8);
  }

  for (int rt = 0; rt < 4; ++rt) {
    const int g = row0 + rt*16 + lr;       // global row (b*196 + tok)
    const int b = g / 196, tok = g - b*196;
    bf16x8 af[4];
    #pragma unroll
    for (int kc = 0; kc < 4; ++kc)         // k-chunk kc == head kc
      af[kc] = *(const bf16x8*)(att + ((size_t)(b*4 + kc)*208 + tok)*32 + lg*8);
    #pragma unroll
    for (int i = 0; i < 2; ++i) {
      f32x4 acc = {0.f,0.f,0.f,0.f};
      #pragma unroll
      for (int kc = 0; kc < 4; ++kc)
        acc = __builtin_amdgcn_mfma_f32_16x16x32_bf16(af[kc], wf[i][kc], acc, 0, 0, 0);
      #pragma unroll
      for (int r = 0; r < 4; ++r)
        out[(size_t)(row0 + rt*16 + lg*4 + r)*DIM + (wave*2 + i)*16 + lr] =
            acc[r] + bias[i];
    }
  }
}

// ---------------------------------------------------------------------------
extern "C" void kernel_launch(void* const* d_in, const int* in_sizes, int n_in,
                              void* d_out, int out_size, void* d_ws, size_t ws_size,
                              hipStream_t stream)
{
  const float* x          = (const float*)d_in[0];
  const float* mask       = (const float*)d_in[1];
  const float* qkv_w      = (const float*)d_in[2];
  const float* qkv_b      = (const float*)d_in[3];
  const float* proj_w     = (const float*)d_in[4];
  const float* proj_b     = (const float*)d_in[5];
  const float* pos_proj_w = (const float*)d_in[6];
  const float* pos_proj_b = (const float*)d_in[7];
  const float* ln1_w = (const float*)d_in[8];
  const float* ln1_b = (const float*)d_in[9];
  const float* fc1_w = (const float*)d_in[10];
  const float* fc1_b = (const float*)d_in[11];
  const float* ln2_w = (const float*)d_in[12];
  const float* ln2_b = (const float*)d_in[13];
  const float* fc2_w = (const float*)d_in[14];
  const float* fc2_b = (const float*)d_in[15];
  const float* ln3_w = (const float*)d_in[16];
  const float* ln3_b = (const float*)d_in[17];
  const float* fc3_w = (const float*)d_in[18];
  const float* fc3_b = (const float*)d_in[19];
  const float* biases = (const float*)d_in[20];
  const int*   rel_idx = (const int*)d_in[21];

  // ws layout (~207 MB — the proven-working layout)
  char* ws = (char*)d_ws;
  unsigned short* wqkv_t  = (unsigned short*)(ws);
  unsigned short* wproj_t = (unsigned short*)(ws + 98304);
  float*          ptab    = (float*)(ws + 131072);
  float*          combT   = (float*)(ws + 147456);              // 39,337,984 B
  unsigned short* q_g     = (unsigned short*)(ws + 39485696);   // 54,525,952 B
  unsigned short* k_g     = (unsigned short*)(ws + 94011648);   // 54,525,952 B
  unsigned short* vt_g    = (unsigned short*)(ws + 148537600);  // 58,720,256 B
  float* out = (float*)d_out;

  prep_kernel<<<8, 256, 0, stream>>>(qkv_w, proj_w, biases, pos_proj_w, pos_proj_b,
      ln1_w, ln1_b, fc1_w, fc1_b, ln2_w, ln2_b, fc2_w, fc2_b,
      ln3_w, ln3_b, fc3_w, fc3_b, wqkv_t, wproj_t, ptab);
  comb_kernel<<<NWIN*N_TOK, 256, 0, stream>>>(rel_idx, ptab, mask, combT);
  qkv_kernel<<<1024, 256, 0, stream>>>(x, qkv_b, wqkv_t, q_g, k_g, vt_g);
  attn_kernel<<<1024*HEADS, 256, 0, stream>>>(q_g, k_g, vt_g, combT);
  proj_kernel<<<(1024*N_TOK)/64, 256, 0, stream>>>(q_g, wproj_t, proj_b, out);
}